// Round 1
// baseline (2387.250 us; speedup 1.0000x reference)
//
#include <hip/hip_runtime.h>

// Conv2dFusion: per (b,s) token, image = outer(type[b,s,:], token[b,s,:]) [128x128].
// Stage0: conv3x3(1->32) + erf-GELU + maxpool2 -> 63x63x32
// Stage1: conv3x3(32->64) + GELU + maxpool2    -> 30x30x64
// Stage2: conv3x3(64->64) + GELU + maxpool2    -> 14x14x64
// Fully fused: 1 block per image, pool0 strip + pool1(bf16) in LDS, zero workspace.

__device__ __forceinline__ float gelu_erf(float x) {
    return 0.5f * x * (1.0f + erff(x * 0.70710678118654752f));
}

__device__ __forceinline__ unsigned short f2bf(float f) {
    unsigned int u = __float_as_uint(f);
    u += 0x7fffu + ((u >> 16) & 1u);   // round-to-nearest-even
    return (unsigned short)(u >> 16);
}
__device__ __forceinline__ float bf2f(unsigned int h16) {
    return __uint_as_float(h16 << 16);
}

// LDS layout (floats):
//   ty[128], tk[128], P0[4*32*63]  then  P1 (ushort) [64*30*30]
#define LDS_BYTES ((128 + 128 + 4*32*63) * 4 + 64*30*30 * 2)

__launch_bounds__(512)
__global__ void conv_pipeline(const float* __restrict__ token,
                              const float* __restrict__ type_,
                              const float* __restrict__ w0, const float* __restrict__ b0,
                              const float* __restrict__ w1, const float* __restrict__ b1,
                              const float* __restrict__ w2, const float* __restrict__ b2,
                              float* __restrict__ out) {
    extern __shared__ unsigned char smem[];
    float* ty = (float*)smem;                   // 128
    float* tk = ty + 128;                       // 128
    float* P0 = tk + 128;                       // [r(4)][c0(32)][q(63)]
    unsigned short* P1 = (unsigned short*)(P0 + 4 * 32 * 63); // [c1(64)][row(30)][col(30)]

    const int tid = threadIdx.x;
    const int img = blockIdx.x;

    for (int i = tid; i < 128; i += 512) {
        ty[i] = type_[img * 128 + i];
        tk[i] = token[img * 128 + i];
    }

    // per-thread conv0 channel (tid&31): stride-512 idx loop keeps c fixed
    const int cw = tid & 31;
    float w0r[9];
    #pragma unroll
    for (int i = 0; i < 9; ++i) w0r[i] = w0[cw * 9 + i];
    const float b0r = b0[cw];

    const int jA = tid & 31;   // conv1 spatial col (0..29 active)
    const int gA = tid >> 5;   // conv1 channel group (0..15) -> c1 = gA + 16k
    float b1r[4];
    #pragma unroll
    for (int k = 0; k < 4; ++k) b1r[k] = b1[gA + 16 * k];

    __syncthreads();

    // ================= Phase A: per pool1-row i1 =================
    for (int i1 = 0; i1 < 30; ++i1) {
        // ---- pool0 strip rows 2i1..2i1+3 (4 x 32 x 63 = 8064 values) ----
        for (int idx = tid; idx < 8064; idx += 512) {
            const int rest = idx >> 5;        // 0..251 ; channel == cw
            const int q = rest % 63;
            const int r = rest / 63;          // 0..3
            const int y0 = 2 * (2 * i1 + r);  // conv0 row base (<=123)
            const int x0 = 2 * q;             // conv0 col base (<=124)
            float m = -3.4e38f;
            #pragma unroll
            for (int a = 0; a < 2; ++a) {
                #pragma unroll
                for (int b = 0; b < 2; ++b) {
                    float s = b0r;
                    #pragma unroll
                    for (int u = 0; u < 3; ++u) {
                        float h = w0r[u*3+0] * tk[x0 + b]
                                + w0r[u*3+1] * tk[x0 + b + 1]
                                + w0r[u*3+2] * tk[x0 + b + 2];
                        s = fmaf(ty[y0 + a + u], h, s);
                    }
                    m = fmaxf(m, gelu_erf(s));
                }
            }
            P0[(r * 32 + cw) * 63 + q] = m;
        }
        __syncthreads();

        // ---- conv1 + GELU + pool -> P1 row i1 ----
        if (jA < 30) {
            float acc[4][2][2];
            #pragma unroll
            for (int k = 0; k < 4; ++k) {
                acc[k][0][0] = b1r[k]; acc[k][0][1] = b1r[k];
                acc[k][1][0] = b1r[k]; acc[k][1][1] = b1r[k];
            }
            for (int c0 = 0; c0 < 32; ++c0) {
                float p[4][4];
                #pragma unroll
                for (int ly = 0; ly < 4; ++ly)
                    #pragma unroll
                    for (int x = 0; x < 4; ++x)
                        p[ly][x] = P0[(ly * 32 + c0) * 63 + 2 * jA + x];
                #pragma unroll
                for (int k = 0; k < 4; ++k) {
                    const float* wp = w1 + (size_t)((gA + 16 * k) * 32 + c0) * 9;
                    #pragma unroll
                    for (int u = 0; u < 3; ++u)
                        #pragma unroll
                        for (int v = 0; v < 3; ++v) {
                            const float w = wp[u * 3 + v];
                            acc[k][0][0] = fmaf(w, p[u    ][v    ], acc[k][0][0]);
                            acc[k][0][1] = fmaf(w, p[u    ][v + 1], acc[k][0][1]);
                            acc[k][1][0] = fmaf(w, p[u + 1][v    ], acc[k][1][0]);
                            acc[k][1][1] = fmaf(w, p[u + 1][v + 1], acc[k][1][1]);
                        }
                }
            }
            #pragma unroll
            for (int k = 0; k < 4; ++k) {
                float m = fmaxf(fmaxf(gelu_erf(acc[k][0][0]), gelu_erf(acc[k][0][1])),
                                fmaxf(gelu_erf(acc[k][1][0]), gelu_erf(acc[k][1][1])));
                P1[((gA + 16 * k) * 30 + i1) * 30 + jA] = f2bf(m);
            }
        }
        __syncthreads();
    }

    // ================= Phase B: conv2 + GELU + pool -> out =================
    const int j2 = tid & 15;   // spatial col (0..13 active)
    const int g2 = tid >> 4;   // 0..31 -> c2 = g2 + 32k
    if (j2 < 14) {
        const float b2r0 = b2[g2], b2r1 = b2[g2 + 32];
        for (int i2 = 0; i2 < 14; ++i2) {
            float acc[2][2][2];
            acc[0][0][0] = b2r0; acc[0][0][1] = b2r0; acc[0][1][0] = b2r0; acc[0][1][1] = b2r0;
            acc[1][0][0] = b2r1; acc[1][0][1] = b2r1; acc[1][1][0] = b2r1; acc[1][1][1] = b2r1;
            for (int c1 = 0; c1 < 64; ++c1) {
                float p[4][4];
                #pragma unroll
                for (int ly = 0; ly < 4; ++ly) {
                    // aligned u32 pair reads of bf16 (cols 2j2..2j2+3)
                    const unsigned int* row =
                        (const unsigned int*)(P1 + ((c1 * 30) + 2 * i2 + ly) * 30 + 2 * j2);
                    const unsigned int a0 = row[0], a1 = row[1];
                    p[ly][0] = bf2f(a0 & 0xffffu);
                    p[ly][1] = bf2f(a0 >> 16);
                    p[ly][2] = bf2f(a1 & 0xffffu);
                    p[ly][3] = bf2f(a1 >> 16);
                }
                #pragma unroll
                for (int k = 0; k < 2; ++k) {
                    const float* wp = w2 + (size_t)((g2 + 32 * k) * 64 + c1) * 9;
                    #pragma unroll
                    for (int u = 0; u < 3; ++u)
                        #pragma unroll
                        for (int v = 0; v < 3; ++v) {
                            const float w = wp[u * 3 + v];
                            acc[k][0][0] = fmaf(w, p[u    ][v    ], acc[k][0][0]);
                            acc[k][0][1] = fmaf(w, p[u    ][v + 1], acc[k][0][1]);
                            acc[k][1][0] = fmaf(w, p[u + 1][v    ], acc[k][1][0]);
                            acc[k][1][1] = fmaf(w, p[u + 1][v + 1], acc[k][1][1]);
                        }
                }
            }
            #pragma unroll
            for (int k = 0; k < 2; ++k) {
                float m = fmaxf(fmaxf(gelu_erf(acc[k][0][0]), gelu_erf(acc[k][0][1])),
                                fmaxf(gelu_erf(acc[k][1][0]), gelu_erf(acc[k][1][1])));
                out[(size_t)img * 12544 + (g2 + 32 * k) * 196 + i2 * 14 + j2] = m;
            }
        }
    }
}

extern "C" void kernel_launch(void* const* d_in, const int* in_sizes, int n_in,
                              void* d_out, int out_size, void* d_ws, size_t ws_size,
                              hipStream_t stream) {
    const float* token = (const float*)d_in[0];
    const float* type_ = (const float*)d_in[1];
    const float* w0 = (const float*)d_in[2];
    const float* b0 = (const float*)d_in[3];
    const float* w1 = (const float*)d_in[4];
    const float* b1 = (const float*)d_in[5];
    const float* w2 = (const float*)d_in[6];
    const float* b2 = (const float*)d_in[7];
    float* out = (float*)d_out;

    hipLaunchKernelGGL(conv_pipeline, dim3(512), dim3(512), LDS_BYTES, stream,
                       token, type_, w0, b0, w1, b1, w2, b2, out);
}

// Round 2
// 299.869 us; speedup vs baseline: 7.9610x; 7.9610x over previous
//
#include <hip/hip_runtime.h>

// Conv2dFusion, MFMA version.
// Per image (b,s): 128x128 rank-1 map -> conv0(1->32)+GELU+pool -> 63x63x32
//   -> conv1(32->64)+GELU+pool -> 30x30x64 -> conv2(64->64)+GELU+pool -> 14x14x64.
// conv0 via H-table (rank-1 trick), conv1/conv2 via mfma_f32_16x16x32_bf16
// implicit GEMM (M=spatial cols, N=Cout, K=Cin, 9 shifted-window accumulations).

typedef short short8 __attribute__((ext_vector_type(8)));
typedef float f32x4 __attribute__((ext_vector_type(4)));

#define OFF_TY   0                    // f32[128]
#define OFF_TK   512                  // f32[128]
#define OFF_HLO  1024                 // u32[32*126]  (bf16 pair u0,u1)
#define OFF_HHI  (1024 + 16128)       // u16[32*126]  (bf16 u2)
#define OFF_P0   25216                // 4 slots * 264 units * 16B = 16896
#define OFF_P1   42112                // 30*30*8 units * 16B = 115200 (+512 pad)
#define LDS_TOTAL (42112 + 115200 + 512)   // 157,824 B

__device__ __forceinline__ unsigned short f2bf(float f) {
    unsigned int u = __float_as_uint(f);
    u += 0x7fffu + ((u >> 16) & 1u);   // RNE
    return (unsigned short)(u >> 16);
}

// erf-GELU via Abramowitz-Stegun 7.1.25 (|err| <= 2.5e-5), branch-free.
__device__ __forceinline__ float gelu_f(float x) {
    float ax = __builtin_fabsf(x);
    float E  = __builtin_amdgcn_exp2f(x * x * -0.72134752f);          // e^{-x^2/2}
    float k  = __builtin_amdgcn_rcpf(__builtin_fmaf(0.33267686f, ax, 1.0f)); // 1/(1+p*|x|/sqrt2)
    float s  = __builtin_fmaf(0.7478556f, k, -0.0958798f);
    s = __builtin_fmaf(s, k, 0.3480242f);
    s = s * k;
    float erfabs = __builtin_fmaf(-s, E, 1.0f);
    return __builtin_fmaf(0.5f * ax, erfabs, 0.5f * x);
}

// pool0 producer: rows R0, R0+1 of the 63x63x32 pooled stage-0 output into P0 ring.
__device__ __forceinline__ void produce(char* smem, const float* tys,
                                        float b0r, int c, int tid, int R0) {
    float t0 = tys[2*R0+0], t1 = tys[2*R0+1], t2 = tys[2*R0+2],
          t3 = tys[2*R0+3], t4 = tys[2*R0+4], t5 = tys[2*R0+5];
    int rest = tid >> 5;
    #pragma unroll
    for (int k = 0; k < 8; ++k, rest += 16) {
        if (rest < 126) {
            int roff = (rest >= 63) ? 1 : 0;
            int q = rest - (roff ? 63 : 0);
            float s0 = roff ? t2 : t0;
            float s1 = roff ? t3 : t1;
            float s2 = roff ? t4 : t2;
            float s3 = roff ? t5 : t3;
            uint2 lo = *(const uint2*)(smem + OFF_HLO + (c*126 + 2*q)*4);
            unsigned int hi = *(const unsigned int*)(smem + OFF_HHI + (c*126 + 2*q)*2);
            float h00 = __uint_as_float(lo.x << 16);
            float h10 = __uint_as_float(lo.x & 0xffff0000u);
            float h01 = __uint_as_float(lo.y << 16);
            float h11 = __uint_as_float(lo.y & 0xffff0000u);
            float h20 = __uint_as_float(hi << 16);
            float h21 = __uint_as_float(hi & 0xffff0000u);
            float e00 = __builtin_fmaf(s0,h00, __builtin_fmaf(s1,h10, __builtin_fmaf(s2,h20, b0r)));
            float e10 = __builtin_fmaf(s1,h00, __builtin_fmaf(s2,h10, __builtin_fmaf(s3,h20, b0r)));
            float e01 = __builtin_fmaf(s0,h01, __builtin_fmaf(s1,h11, __builtin_fmaf(s2,h21, b0r)));
            float e11 = __builtin_fmaf(s1,h01, __builtin_fmaf(s2,h11, __builtin_fmaf(s3,h21, b0r)));
            float m = fmaxf(fmaxf(gelu_f(e00), gelu_f(e01)),
                            fmaxf(gelu_f(e10), gelu_f(e11)));
            int slot = (R0 + roff) & 3;
            int unit = slot*264 + (q>>1)*8 + ((4*(q&1) + (c>>3)) ^ ((q>>1)&7));
            *(unsigned short*)(smem + OFF_P0 + unit*16 + (c&7)*2) = f2bf(m);
        }
    }
}

__launch_bounds__(512, 2)
__global__ void conv_pipeline(const float* __restrict__ token,
                              const float* __restrict__ type_,
                              const float* __restrict__ w0, const float* __restrict__ b0,
                              const float* __restrict__ w1, const float* __restrict__ b1,
                              const float* __restrict__ w2, const float* __restrict__ b2,
                              float* __restrict__ out) {
    extern __shared__ char smem[];
    float* tys = (float*)(smem + OFF_TY);
    float* tks = (float*)(smem + OFF_TK);

    const int tid = threadIdx.x;
    const int img = blockIdx.x;
    const int w   = tid >> 6;
    const int l   = tid & 63;
    const int l15 = l & 15;
    const int lc  = l >> 4;
    const int c0w = tid & 31;

    for (int i = tid; i < 128; i += 512) {
        tys[i] = type_[img*128 + i];
        tks[i] = token[img*128 + i];
    }

    float w0r[9];
    #pragma unroll
    for (int i = 0; i < 9; ++i) w0r[i] = w0[c0w*9 + i];
    const float b0r = b0[c0w];

    // conv1 roles: wave w -> mtile (16 cols) mt1, ntile-group ng (ntiles 2ng,2ng+1)
    const int mt1 = w >> 1, ng = w & 1;
    short8 b1f[9][2];
    float bias1[2];
    #pragma unroll
    for (int nt = 0; nt < 2; ++nt) {
        int c1 = (2*ng + nt)*16 + l15;
        bias1[nt] = b1[c1];
        #pragma unroll
        for (int uv = 0; uv < 9; ++uv) {
            short8 f;
            #pragma unroll
            for (int j = 0; j < 8; ++j)
                f[j] = (short)f2bf(w1[(c1*32 + 8*lc + j)*9 + uv]);
            b1f[uv][nt] = f;
        }
    }

    __syncthreads();

    // Build H[c][x][u] = sum_v w0[c,u,v]*tk[x+v], split lo(u0,u1)/hi(u2), bf16.
    {
        int x = tid >> 5;
        #pragma unroll
        for (int k = 0; k < 8; ++k, x += 16) {
            if (x < 126) {
                float t0 = tks[x], t1 = tks[x+1], t2 = tks[x+2];
                float h0 = __builtin_fmaf(w0r[0],t0, __builtin_fmaf(w0r[1],t1, w0r[2]*t2));
                float h1 = __builtin_fmaf(w0r[3],t0, __builtin_fmaf(w0r[4],t1, w0r[5]*t2));
                float h2 = __builtin_fmaf(w0r[6],t0, __builtin_fmaf(w0r[7],t1, w0r[8]*t2));
                unsigned int lo = (unsigned int)f2bf(h0) | ((unsigned int)f2bf(h1) << 16);
                *(unsigned int*)(smem + OFF_HLO + (c0w*126 + x)*4) = lo;
                *(unsigned short*)(smem + OFF_HHI + (c0w*126 + x)*2) = f2bf(h2);
            }
        }
    }
    __syncthreads();

    produce(smem, tys, b0r, c0w, tid, 0);
    produce(smem, tys, b0r, c0w, tid, 2);

    // ============ main loop over pool1 rows ============
    for (int i1 = 0; i1 < 30; ++i1) {
        __syncthreads();
        f32x4 acc[2][2];
        #pragma unroll
        for (int r = 0; r < 2; ++r)
            #pragma unroll
            for (int nt = 0; nt < 2; ++nt)
                acc[r][nt] = (f32x4){0.f,0.f,0.f,0.f};

        #pragma unroll
        for (int pr = 0; pr < 4; ++pr) {
            int sbase = ((2*i1 + pr) & 3) * 264;
            #pragma unroll
            for (int v = 0; v < 3; ++v) {
                int col = mt1*16 + l15 + v;
                int unit = sbase + (col>>1)*8 + ((4*(col&1) + lc) ^ ((col>>1)&7));
                short8 a = *(const short8*)(smem + OFF_P0 + unit*16);
                #pragma unroll
                for (int nt = 0; nt < 2; ++nt) {
                    if (pr <= 2)
                        acc[0][nt] = __builtin_amdgcn_mfma_f32_16x16x32_bf16(
                            a, b1f[pr*3+v][nt], acc[0][nt], 0, 0, 0);
                    if (pr >= 1)
                        acc[1][nt] = __builtin_amdgcn_mfma_f32_16x16x32_bf16(
                            a, b1f[(pr-1)*3+v][nt], acc[1][nt], 0, 0, 0);
                }
            }
        }

        // epilogue: bias+GELU+2x2 pool -> P1 row i1 (bf16, swizzled)
        int pcol = mt1*8 + lc*2;
        if (pcol < 30) {
            #pragma unroll
            for (int nt = 0; nt < 2; ++nt) {
                float g00 = gelu_f(acc[0][nt][0] + bias1[nt]);
                float g01 = gelu_f(acc[0][nt][1] + bias1[nt]);
                float g02 = gelu_f(acc[0][nt][2] + bias1[nt]);
                float g03 = gelu_f(acc[0][nt][3] + bias1[nt]);
                float g10 = gelu_f(acc[1][nt][0] + bias1[nt]);
                float g11 = gelu_f(acc[1][nt][1] + bias1[nt]);
                float g12 = gelu_f(acc[1][nt][2] + bias1[nt]);
                float g13 = gelu_f(acc[1][nt][3] + bias1[nt]);
                float m0 = fmaxf(fmaxf(g00, g01), fmaxf(g10, g11));
                float m1 = fmaxf(fmaxf(g02, g03), fmaxf(g12, g13));
                int c1 = (2*ng + nt)*16 + l15;
                int ubase = (i1*30 + pcol)*8;
                int xr = c1 >> 3;
                int u0 = ubase + (xr ^ (pcol & 7));
                int u1 = ubase + 8 + (xr ^ ((pcol+1) & 7));
                *(unsigned short*)(smem + OFF_P1 + u0*16 + (c1&7)*2) = f2bf(m0);
                *(unsigned short*)(smem + OFF_P1 + u1*16 + (c1&7)*2) = f2bf(m1);
            }
        }
        __syncthreads();
        if (i1 < 29) produce(smem, tys, b0r, c0w, tid, 2*i1 + 4);
    }

    __syncthreads();

    // ============ conv2 + GELU + pool -> out ============
    const int mt2 = w >> 2, nt2 = w & 3;
    const int c2 = nt2*16 + l15;
    const float b2r = b2[c2];
    short8 b2f[9][2];
    #pragma unroll
    for (int kh = 0; kh < 2; ++kh)
        #pragma unroll
        for (int uv = 0; uv < 9; ++uv) {
            short8 f;
            #pragma unroll
            for (int j = 0; j < 8; ++j)
                f[j] = (short)f2bf(w2[(c2*64 + kh*32 + 8*lc + j)*9 + uv]);
            b2f[uv][kh] = f;
        }

    const size_t obase = (size_t)img * 12544;
    for (int i2 = 0; i2 < 14; ++i2) {
        f32x4 a2[2];
        a2[0] = (f32x4){0.f,0.f,0.f,0.f};
        a2[1] = (f32x4){0.f,0.f,0.f,0.f};
        #pragma unroll
        for (int pr = 0; pr < 4; ++pr) {
            int rb = (2*i2 + pr)*30;
            #pragma unroll
            for (int v = 0; v < 3; ++v) {
                int col = mt2*16 + l15 + v;
                int ub = (rb + col)*8;
                #pragma unroll
                for (int kh = 0; kh < 2; ++kh) {
                    int unit = ub + ((kh*4 + lc) ^ (col & 7));
                    short8 a = *(const short8*)(smem + OFF_P1 + unit*16);
                    if (pr <= 2)
                        a2[0] = __builtin_amdgcn_mfma_f32_16x16x32_bf16(
                            a, b2f[pr*3+v][kh], a2[0], 0, 0, 0);
                    if (pr >= 1)
                        a2[1] = __builtin_amdgcn_mfma_f32_16x16x32_bf16(
                            a, b2f[(pr-1)*3+v][kh], a2[1], 0, 0, 0);
                }
            }
        }
        int pcol = mt2*8 + lc*2;
        if (pcol < 14) {
            float g00 = gelu_f(a2[0][0] + b2r);
            float g01 = gelu_f(a2[0][1] + b2r);
            float g02 = gelu_f(a2[0][2] + b2r);
            float g03 = gelu_f(a2[0][3] + b2r);
            float g10 = gelu_f(a2[1][0] + b2r);
            float g11 = gelu_f(a2[1][1] + b2r);
            float g12 = gelu_f(a2[1][2] + b2r);
            float g13 = gelu_f(a2[1][3] + b2r);
            float m0 = fmaxf(fmaxf(g00, g01), fmaxf(g10, g11));
            float m1 = fmaxf(fmaxf(g02, g03), fmaxf(g12, g13));
            float2 st; st.x = m0; st.y = m1;
            *(float2*)(out + obase + c2*196 + i2*14 + pcol) = st;
        }
    }
}

extern "C" void kernel_launch(void* const* d_in, const int* in_sizes, int n_in,
                              void* d_out, int out_size, void* d_ws, size_t ws_size,
                              hipStream_t stream) {
    const float* token = (const float*)d_in[0];
    const float* type_ = (const float*)d_in[1];
    const float* w0 = (const float*)d_in[2];
    const float* b0 = (const float*)d_in[3];
    const float* w1 = (const float*)d_in[4];
    const float* b1 = (const float*)d_in[5];
    const float* w2 = (const float*)d_in[6];
    const float* b2 = (const float*)d_in[7];
    float* out = (float*)d_out;

    hipLaunchKernelGGL(conv_pipeline, dim3(512), dim3(512), LDS_TOTAL, stream,
                       token, type_, w0, b0, w1, b1, w2, b2, out);
}

// Round 3
// 254.267 us; speedup vs baseline: 9.3888x; 1.1793x over previous
//
#include <hip/hip_runtime.h>

// Conv2dFusion v3: wave-specialized fused pipeline, 2 blocks/CU.
// Per image: 128x128 rank-1 map -> conv0(1->32)+GELU+pool (VALU, H-table, GELU-after-max)
//   -> conv1(32->64)+GELU+pool (MFMA, waves 0-3) -> P1 6-row LDS ring
//   -> conv2(64->64)+GELU+pool (MFMA, waves 4-7, interleaved) -> out.
// LDS 65.7KB -> 2 blocks/CU; shared wf[18] frag array keeps VGPR <= 128.

typedef short short8 __attribute__((ext_vector_type(8)));
typedef float f32x4 __attribute__((ext_vector_type(4)));

#define OFF_TY   0                    // f32[128]
#define OFF_TK   512                  // f32[128]
#define OFF_HLO  1024                 // u32[32*126]
#define OFF_HHI  (1024 + 16128)       // u16[32*126]
#define OFF_P0   (17152 + 8064)       // 25216: 4 slots * 264 units * 16B
#define OFF_P1   (25216 + 16896)      // 42112: ring 6 rows*240 units + 32 pad = 1472 units
#define LDS_TOTAL (42112 + 1472*16)   // 65,664 B

__device__ __forceinline__ unsigned short f2bf(float f) {
    unsigned int u = __float_as_uint(f);
    u += 0x7fffu + ((u >> 16) & 1u);   // RNE
    return (unsigned short)(u >> 16);
}

// erf-GELU via A&S 7.1.25 (|err| <= 2.5e-5), branch-free.
__device__ __forceinline__ float gelu_f(float x) {
    float ax = __builtin_fabsf(x);
    float E  = __builtin_amdgcn_exp2f(x * x * -0.72134752f);
    float k  = __builtin_amdgcn_rcpf(__builtin_fmaf(0.33267686f, ax, 1.0f));
    float s  = __builtin_fmaf(0.7478556f, k, -0.0958798f);
    s = __builtin_fmaf(s, k, 0.3480242f);
    s = s * k;
    float erfabs = __builtin_fmaf(-s, E, 1.0f);
    return __builtin_fmaf(0.5f * ax, erfabs, 0.5f * x);
}

// pool0 producer: pooled rows R0, R0+1 into P0 ring (GELU applied after max).
__device__ __forceinline__ void produce(char* smem, const float* tys,
                                        float b0r, int c, int tid, int R0) {
    float t0 = tys[2*R0+0], t1 = tys[2*R0+1], t2 = tys[2*R0+2],
          t3 = tys[2*R0+3], t4 = tys[2*R0+4], t5 = tys[2*R0+5];
    int rest = tid >> 5;
    #pragma unroll
    for (int k = 0; k < 8; ++k, rest += 16) {
        if (rest < 126) {
            int roff = (rest >= 63) ? 1 : 0;
            int q = rest - (roff ? 63 : 0);
            float s0 = roff ? t2 : t0;
            float s1 = roff ? t3 : t1;
            float s2 = roff ? t4 : t2;
            float s3 = roff ? t5 : t3;
            uint2 lo = *(const uint2*)(smem + OFF_HLO + (c*126 + 2*q)*4);
            unsigned int hi = *(const unsigned int*)(smem + OFF_HHI + (c*126 + 2*q)*2);
            float h00 = __uint_as_float(lo.x << 16);
            float h10 = __uint_as_float(lo.x & 0xffff0000u);
            float h01 = __uint_as_float(lo.y << 16);
            float h11 = __uint_as_float(lo.y & 0xffff0000u);
            float h20 = __uint_as_float(hi << 16);
            float h21 = __uint_as_float(hi & 0xffff0000u);
            float e00 = __builtin_fmaf(s0,h00, __builtin_fmaf(s1,h10, __builtin_fmaf(s2,h20, b0r)));
            float e10 = __builtin_fmaf(s1,h00, __builtin_fmaf(s2,h10, __builtin_fmaf(s3,h20, b0r)));
            float e01 = __builtin_fmaf(s0,h01, __builtin_fmaf(s1,h11, __builtin_fmaf(s2,h21, b0r)));
            float e11 = __builtin_fmaf(s1,h01, __builtin_fmaf(s2,h11, __builtin_fmaf(s3,h21, b0r)));
            // GELU after max (monotone for x>-0.75; bias bounded & smoothed downstream)
            float m = gelu_f(fmaxf(fmaxf(e00, e01), fmaxf(e10, e11)));
            int slot = (R0 + roff) & 3;
            int unit = slot*264 + (q>>1)*8 + ((4*(q&1) + (c>>3)) ^ ((q>>1)&7));
            *(unsigned short*)(smem + OFF_P0 + unit*16 + (c&7)*2) = f2bf(m);
        }
    }
}

__launch_bounds__(512, 4)
__global__ void conv_pipeline(const float* __restrict__ token,
                              const float* __restrict__ type_,
                              const float* __restrict__ w0, const float* __restrict__ b0,
                              const float* __restrict__ w1, const float* __restrict__ b1,
                              const float* __restrict__ w2, const float* __restrict__ b2,
                              float* __restrict__ out) {
    extern __shared__ char smem[];
    float* tys = (float*)(smem + OFF_TY);
    float* tks = (float*)(smem + OFF_TK);

    const int tid = threadIdx.x;
    const int img = blockIdx.x;
    const int w   = tid >> 6;
    const int l   = tid & 63;
    const int l15 = l & 15;
    const int lc  = l >> 4;
    const int c0w = tid & 31;

    for (int i = tid; i < 128; i += 512) {
        tys[i] = type_[img*128 + i];
        tks[i] = token[img*128 + i];
    }

    float w0r[9];
    #pragma unroll
    for (int i = 0; i < 9; ++i) w0r[i] = w0[c0w*9 + i];
    const float b0r = b0[c0w];

    // Shared fragment storage: waves 0-3 use wf[0..8] (conv1, nt=w),
    // waves 4-7 use wf[0..17] (conv2, nt=w-4, kh*9+uv).
    short8 wf[18];
    float bias;
    const int ch = ((w & 3) * 16) + l15;       // c1 (waves<4) or c2 (waves>=4)
    if (w < 4) {
        bias = b1[ch];
        #pragma unroll
        for (int uv = 0; uv < 9; ++uv) {
            short8 f;
            #pragma unroll
            for (int j = 0; j < 8; ++j)
                f[j] = (short)f2bf(w1[(ch*32 + 8*lc + j)*9 + uv]);
            wf[uv] = f;
        }
    } else {
        bias = b2[ch];
        #pragma unroll
        for (int kh = 0; kh < 2; ++kh)
            #pragma unroll
            for (int uv = 0; uv < 9; ++uv) {
                short8 f;
                #pragma unroll
                for (int j = 0; j < 8; ++j)
                    f[j] = (short)f2bf(w2[(ch*64 + kh*32 + 8*lc + j)*9 + uv]);
                wf[kh*9 + uv] = f;
            }
    }

    __syncthreads();   // ty/tk visible

    // H[c][x][u] = sum_v w0[c,u,v]*tk[x+v]
    {
        int x = tid >> 5;
        #pragma unroll
        for (int k = 0; k < 8; ++k, x += 16) {
            if (x < 126) {
                float t0 = tks[x], t1 = tks[x+1], t2 = tks[x+2];
                float h0 = __builtin_fmaf(w0r[0],t0, __builtin_fmaf(w0r[1],t1, w0r[2]*t2));
                float h1 = __builtin_fmaf(w0r[3],t0, __builtin_fmaf(w0r[4],t1, w0r[5]*t2));
                float h2 = __builtin_fmaf(w0r[6],t0, __builtin_fmaf(w0r[7],t1, w0r[8]*t2));
                unsigned int lov = (unsigned int)f2bf(h0) | ((unsigned int)f2bf(h1) << 16);
                *(unsigned int*)(smem + OFF_HLO + (c0w*126 + x)*4) = lov;
                *(unsigned short*)(smem + OFF_HHI + (c0w*126 + x)*2) = f2bf(h2);
            }
        }
    }
    __syncthreads();   // H visible

    produce(smem, tys, b0r, c0w, tid, 0);
    produce(smem, tys, b0r, c0w, tid, 2);

    const size_t obase = (size_t)img * 12544;

    for (int i1 = 0; i1 < 30; ++i1) {
        __syncthreads();   // P0 strip + P1[i1-1] visible

        if (w < 4) {
            // ---------- conv1 row i1: waves 0-3, nt=w, all 4 mtiles ----------
            f32x4 acc[8];   // [mt][row]
            #pragma unroll
            for (int i = 0; i < 8; ++i) acc[i] = (f32x4){0.f,0.f,0.f,0.f};
            #pragma unroll
            for (int pr = 0; pr < 4; ++pr) {
                int sbase = ((2*i1 + pr) & 3) * 264;
                #pragma unroll
                for (int v = 0; v < 3; ++v) {
                    #pragma unroll
                    for (int mt = 0; mt < 4; ++mt) {
                        int col = mt*16 + l15 + v;
                        int unit = sbase + (col>>1)*8 + ((4*(col&1) + lc) ^ ((col>>1)&7));
                        short8 a = *(const short8*)(smem + OFF_P0 + unit*16);
                        if (pr <= 2)
                            acc[mt*2+0] = __builtin_amdgcn_mfma_f32_16x16x32_bf16(
                                a, wf[pr*3+v], acc[mt*2+0], 0, 0, 0);
                        if (pr >= 1)
                            acc[mt*2+1] = __builtin_amdgcn_mfma_f32_16x16x32_bf16(
                                a, wf[(pr-1)*3+v], acc[mt*2+1], 0, 0, 0);
                    }
                }
            }
            // epilogue: premax -> +bias -> GELU -> P1 ring row i1%6
            int rbase = (i1 % 6) * 30;
            int xr = ch >> 3;
            #pragma unroll
            for (int mt = 0; mt < 4; ++mt) {
                int pcol = mt*8 + lc*2;
                if (pcol < 30) {
                    f32x4 A0 = acc[mt*2+0], A1 = acc[mt*2+1];
                    float p0 = fmaxf(fmaxf(A0[0], A0[1]), fmaxf(A1[0], A1[1]));
                    float p1 = fmaxf(fmaxf(A0[2], A0[3]), fmaxf(A1[2], A1[3]));
                    float m0 = gelu_f(p0 + bias);
                    float m1 = gelu_f(p1 + bias);
                    int u0 = (rbase + pcol)*8     + (xr ^ (pcol & 7));
                    int u1 = (rbase + pcol + 1)*8 + (xr ^ ((pcol+1) & 7));
                    *(unsigned short*)(smem + OFF_P1 + u0*16 + (ch&7)*2) = f2bf(m0);
                    *(unsigned short*)(smem + OFF_P1 + u1*16 + (ch&7)*2) = f2bf(m1);
                }
            }
        } else if (i1 >= 4 && (i1 & 1) == 0) {
            // ---------- conv2 row i2: waves 4-7, nt=w-4, 2 mtiles ----------
            const int i2 = (i1 - 4) >> 1;
            f32x4 acc[4];   // [mt][row]
            #pragma unroll
            for (int i = 0; i < 4; ++i) acc[i] = (f32x4){0.f,0.f,0.f,0.f};
            #pragma unroll
            for (int pr = 0; pr < 4; ++pr) {
                int rb = ((2*i2 + pr) % 6) * 30;
                #pragma unroll
                for (int v = 0; v < 3; ++v) {
                    #pragma unroll
                    for (int mt = 0; mt < 2; ++mt) {
                        int col = mt*16 + l15 + v;
                        #pragma unroll
                        for (int kh = 0; kh < 2; ++kh) {
                            int unit = (rb + col)*8 + ((kh*4 + lc) ^ (col & 7));
                            short8 a = *(const short8*)(smem + OFF_P1 + unit*16);
                            if (pr <= 2)
                                acc[mt*2+0] = __builtin_amdgcn_mfma_f32_16x16x32_bf16(
                                    a, wf[kh*9 + pr*3+v], acc[mt*2+0], 0, 0, 0);
                            if (pr >= 1)
                                acc[mt*2+1] = __builtin_amdgcn_mfma_f32_16x16x32_bf16(
                                    a, wf[kh*9 + (pr-1)*3+v], acc[mt*2+1], 0, 0, 0);
                        }
                    }
                }
            }
            // epilogue: exact GELU x8 then max -> out
            #pragma unroll
            for (int mt = 0; mt < 2; ++mt) {
                int pcol = mt*8 + lc*2;
                if (pcol < 14) {
                    f32x4 A0 = acc[mt*2+0], A1 = acc[mt*2+1];
                    float g00 = gelu_f(A0[0] + bias), g01 = gelu_f(A0[1] + bias);
                    float g02 = gelu_f(A0[2] + bias), g03 = gelu_f(A0[3] + bias);
                    float g10 = gelu_f(A1[0] + bias), g11 = gelu_f(A1[1] + bias);
                    float g12 = gelu_f(A1[2] + bias), g13 = gelu_f(A1[3] + bias);
                    float m0 = fmaxf(fmaxf(g00, g01), fmaxf(g10, g11));
                    float m1 = fmaxf(fmaxf(g02, g03), fmaxf(g12, g13));
                    float2 st; st.x = m0; st.y = m1;
                    *(float2*)(out + obase + ch*196 + i2*14 + pcol) = st;
                }
            }
        }

        __syncthreads();   // conv1 reads of P0 done; P1 row i1 done
        if (i1 < 29) produce(smem, tys, b0r, c0w, tid, 2*i1 + 4);
    }

    __syncthreads();
    // tail: conv2 row 13 (P1 rows 26..29)
    if (w >= 4) {
        const int i2 = 13;
        f32x4 acc[4];
        #pragma unroll
        for (int i = 0; i < 4; ++i) acc[i] = (f32x4){0.f,0.f,0.f,0.f};
        #pragma unroll
        for (int pr = 0; pr < 4; ++pr) {
            int rb = ((2*i2 + pr) % 6) * 30;
            #pragma unroll
            for (int v = 0; v < 3; ++v) {
                #pragma unroll
                for (int mt = 0; mt < 2; ++mt) {
                    int col = mt*16 + l15 + v;
                    #pragma unroll
                    for (int kh = 0; kh < 2; ++kh) {
                        int unit = (rb + col)*8 + ((kh*4 + lc) ^ (col & 7));
                        short8 a = *(const short8*)(smem + OFF_P1 + unit*16);
                        if (pr <= 2)
                            acc[mt*2+0] = __builtin_amdgcn_mfma_f32_16x16x32_bf16(
                                a, wf[kh*9 + pr*3+v], acc[mt*2+0], 0, 0, 0);
                        if (pr >= 1)
                            acc[mt*2+1] = __builtin_amdgcn_mfma_f32_16x16x32_bf16(
                                a, wf[kh*9 + (pr-1)*3+v], acc[mt*2+1], 0, 0, 0);
                    }
                }
            }
        }
        #pragma unroll
        for (int mt = 0; mt < 2; ++mt) {
            int pcol = mt*8 + lc*2;
            if (pcol < 14) {
                f32x4 A0 = acc[mt*2+0], A1 = acc[mt*2+1];
                float g00 = gelu_f(A0[0] + bias), g01 = gelu_f(A0[1] + bias);
                float g02 = gelu_f(A0[2] + bias), g03 = gelu_f(A0[3] + bias);
                float g10 = gelu_f(A1[0] + bias), g11 = gelu_f(A1[1] + bias);
                float g12 = gelu_f(A1[2] + bias), g13 = gelu_f(A1[3] + bias);
                float m0 = fmaxf(fmaxf(g00, g01), fmaxf(g10, g11));
                float m1 = fmaxf(fmaxf(g02, g03), fmaxf(g12, g13));
                float2 st; st.x = m0; st.y = m1;
                *(float2*)(out + obase + ch*196 + i2*14 + pcol) = st;
            }
        }
    }
}

extern "C" void kernel_launch(void* const* d_in, const int* in_sizes, int n_in,
                              void* d_out, int out_size, void* d_ws, size_t ws_size,
                              hipStream_t stream) {
    const float* token = (const float*)d_in[0];
    const float* type_ = (const float*)d_in[1];
    const float* w0 = (const float*)d_in[2];
    const float* b0 = (const float*)d_in[3];
    const float* w1 = (const float*)d_in[4];
    const float* b1 = (const float*)d_in[5];
    const float* w2 = (const float*)d_in[6];
    const float* b2 = (const float*)d_in[7];
    float* out = (float*)d_out;

    hipLaunchKernelGGL(conv_pipeline, dim3(512), dim3(512), LDS_TOTAL, stream,
                       token, type_, w0, b0, w1, b1, w2, b2, out);
}

// Round 4
// 254.007 us; speedup vs baseline: 9.3984x; 1.0010x over previous
//
#include <hip/hip_runtime.h>

// Conv2dFusion v3: wave-specialized fused pipeline, 2 blocks/CU.
// Per image: 128x128 rank-1 map -> conv0(1->32)+GELU+pool (VALU, H-table, GELU-after-max)
//   -> conv1(32->64)+GELU+pool (MFMA, waves 0-3) -> P1 6-row LDS ring
//   -> conv2(64->64)+GELU+pool (MFMA, waves 4-7, interleaved) -> out.
// LDS 65.7KB -> 2 blocks/CU; shared wf[18] frag array keeps VGPR <= 128.

typedef short short8 __attribute__((ext_vector_type(8)));
typedef float f32x4 __attribute__((ext_vector_type(4)));

#define OFF_TY   0                    // f32[128]
#define OFF_TK   512                  // f32[128]
#define OFF_HLO  1024                 // u32[32*126]
#define OFF_HHI  (1024 + 16128)       // u16[32*126]
#define OFF_P0   (17152 + 8064)       // 25216: 4 slots * 264 units * 16B
#define OFF_P1   (25216 + 16896)      // 42112: ring 6 rows*240 units + 32 pad = 1472 units
#define LDS_TOTAL (42112 + 1472*16)   // 65,664 B

__device__ __forceinline__ unsigned short f2bf(float f) {
    unsigned int u = __float_as_uint(f);
    u += 0x7fffu + ((u >> 16) & 1u);   // RNE
    return (unsigned short)(u >> 16);
}

// erf-GELU via A&S 7.1.25 (|err| <= 2.5e-5), branch-free.
__device__ __forceinline__ float gelu_f(float x) {
    float ax = __builtin_fabsf(x);
    float E  = __builtin_amdgcn_exp2f(x * x * -0.72134752f);
    float k  = __builtin_amdgcn_rcpf(__builtin_fmaf(0.33267686f, ax, 1.0f));
    float s  = __builtin_fmaf(0.7478556f, k, -0.0958798f);
    s = __builtin_fmaf(s, k, 0.3480242f);
    s = s * k;
    float erfabs = __builtin_fmaf(-s, E, 1.0f);
    return __builtin_fmaf(0.5f * ax, erfabs, 0.5f * x);
}

// pool0 producer: pooled rows R0, R0+1 into P0 ring (GELU applied after max).
__device__ __forceinline__ void produce(char* smem, const float* tys,
                                        float b0r, int c, int tid, int R0) {
    float t0 = tys[2*R0+0], t1 = tys[2*R0+1], t2 = tys[2*R0+2],
          t3 = tys[2*R0+3], t4 = tys[2*R0+4], t5 = tys[2*R0+5];
    int rest = tid >> 5;
    #pragma unroll
    for (int k = 0; k < 8; ++k, rest += 16) {
        if (rest < 126) {
            int roff = (rest >= 63) ? 1 : 0;
            int q = rest - (roff ? 63 : 0);
            float s0 = roff ? t2 : t0;
            float s1 = roff ? t3 : t1;
            float s2 = roff ? t4 : t2;
            float s3 = roff ? t5 : t3;
            uint2 lo = *(const uint2*)(smem + OFF_HLO + (c*126 + 2*q)*4);
            unsigned int hi = *(const unsigned int*)(smem + OFF_HHI + (c*126 + 2*q)*2);
            float h00 = __uint_as_float(lo.x << 16);
            float h10 = __uint_as_float(lo.x & 0xffff0000u);
            float h01 = __uint_as_float(lo.y << 16);
            float h11 = __uint_as_float(lo.y & 0xffff0000u);
            float h20 = __uint_as_float(hi << 16);
            float h21 = __uint_as_float(hi & 0xffff0000u);
            float e00 = __builtin_fmaf(s0,h00, __builtin_fmaf(s1,h10, __builtin_fmaf(s2,h20, b0r)));
            float e10 = __builtin_fmaf(s1,h00, __builtin_fmaf(s2,h10, __builtin_fmaf(s3,h20, b0r)));
            float e01 = __builtin_fmaf(s0,h01, __builtin_fmaf(s1,h11, __builtin_fmaf(s2,h21, b0r)));
            float e11 = __builtin_fmaf(s1,h01, __builtin_fmaf(s2,h11, __builtin_fmaf(s3,h21, b0r)));
            // GELU after max (monotone for x>-0.75; bias bounded & smoothed downstream)
            float m = gelu_f(fmaxf(fmaxf(e00, e01), fmaxf(e10, e11)));
            int slot = (R0 + roff) & 3;
            int unit = slot*264 + (q>>1)*8 + ((4*(q&1) + (c>>3)) ^ ((q>>1)&7));
            *(unsigned short*)(smem + OFF_P0 + unit*16 + (c&7)*2) = f2bf(m);
        }
    }
}

__launch_bounds__(512, 4)
__global__ void conv_pipeline(const float* __restrict__ token,
                              const float* __restrict__ type_,
                              const float* __restrict__ w0, const float* __restrict__ b0,
                              const float* __restrict__ w1, const float* __restrict__ b1,
                              const float* __restrict__ w2, const float* __restrict__ b2,
                              float* __restrict__ out) {
    extern __shared__ char smem[];
    float* tys = (float*)(smem + OFF_TY);
    float* tks = (float*)(smem + OFF_TK);

    const int tid = threadIdx.x;
    const int img = blockIdx.x;
    const int w   = tid >> 6;
    const int l   = tid & 63;
    const int l15 = l & 15;
    const int lc  = l >> 4;
    const int c0w = tid & 31;

    for (int i = tid; i < 128; i += 512) {
        tys[i] = type_[img*128 + i];
        tks[i] = token[img*128 + i];
    }

    float w0r[9];
    #pragma unroll
    for (int i = 0; i < 9; ++i) w0r[i] = w0[c0w*9 + i];
    const float b0r = b0[c0w];

    // Shared fragment storage: waves 0-3 use wf[0..8] (conv1, nt=w),
    // waves 4-7 use wf[0..17] (conv2, nt=w-4, kh*9+uv).
    short8 wf[18];
    float bias;
    const int ch = ((w & 3) * 16) + l15;       // c1 (waves<4) or c2 (waves>=4)
    if (w < 4) {
        bias = b1[ch];
        #pragma unroll
        for (int uv = 0; uv < 9; ++uv) {
            short8 f;
            #pragma unroll
            for (int j = 0; j < 8; ++j)
                f[j] = (short)f2bf(w1[(ch*32 + 8*lc + j)*9 + uv]);
            wf[uv] = f;
        }
    } else {
        bias = b2[ch];
        #pragma unroll
        for (int kh = 0; kh < 2; ++kh)
            #pragma unroll
            for (int uv = 0; uv < 9; ++uv) {
                short8 f;
                #pragma unroll
                for (int j = 0; j < 8; ++j)
                    f[j] = (short)f2bf(w2[(ch*64 + kh*32 + 8*lc + j)*9 + uv]);
                wf[kh*9 + uv] = f;
            }
    }

    __syncthreads();   // ty/tk visible

    // H[c][x][u] = sum_v w0[c,u,v]*tk[x+v]
    {
        int x = tid >> 5;
        #pragma unroll
        for (int k = 0; k < 8; ++k, x += 16) {
            if (x < 126) {
                float t0 = tks[x], t1 = tks[x+1], t2 = tks[x+2];
                float h0 = __builtin_fmaf(w0r[0],t0, __builtin_fmaf(w0r[1],t1, w0r[2]*t2));
                float h1 = __builtin_fmaf(w0r[3],t0, __builtin_fmaf(w0r[4],t1, w0r[5]*t2));
                float h2 = __builtin_fmaf(w0r[6],t0, __builtin_fmaf(w0r[7],t1, w0r[8]*t2));
                unsigned int lov = (unsigned int)f2bf(h0) | ((unsigned int)f2bf(h1) << 16);
                *(unsigned int*)(smem + OFF_HLO + (c0w*126 + x)*4) = lov;
                *(unsigned short*)(smem + OFF_HHI + (c0w*126 + x)*2) = f2bf(h2);
            }
        }
    }
    __syncthreads();   // H visible

    produce(smem, tys, b0r, c0w, tid, 0);
    produce(smem, tys, b0r, c0w, tid, 2);

    const size_t obase = (size_t)img * 12544;

    for (int i1 = 0; i1 < 30; ++i1) {
        __syncthreads();   // P0 strip + P1[i1-1] visible

        if (w < 4) {
            // ---------- conv1 row i1: waves 0-3, nt=w, all 4 mtiles ----------
            f32x4 acc[8];   // [mt][row]
            #pragma unroll
            for (int i = 0; i < 8; ++i) acc[i] = (f32x4){0.f,0.f,0.f,0.f};
            #pragma unroll
            for (int pr = 0; pr < 4; ++pr) {
                int sbase = ((2*i1 + pr) & 3) * 264;
                #pragma unroll
                for (int v = 0; v < 3; ++v) {
                    #pragma unroll
                    for (int mt = 0; mt < 4; ++mt) {
                        int col = mt*16 + l15 + v;
                        int unit = sbase + (col>>1)*8 + ((4*(col&1) + lc) ^ ((col>>1)&7));
                        short8 a = *(const short8*)(smem + OFF_P0 + unit*16);
                        if (pr <= 2)
                            acc[mt*2+0] = __builtin_amdgcn_mfma_f32_16x16x32_bf16(
                                a, wf[pr*3+v], acc[mt*2+0], 0, 0, 0);
                        if (pr >= 1)
                            acc[mt*2+1] = __builtin_amdgcn_mfma_f32_16x16x32_bf16(
                                a, wf[(pr-1)*3+v], acc[mt*2+1], 0, 0, 0);
                    }
                }
            }
            // epilogue: premax -> +bias -> GELU -> P1 ring row i1%6
            int rbase = (i1 % 6) * 30;
            int xr = ch >> 3;
            #pragma unroll
            for (int mt = 0; mt < 4; ++mt) {
                int pcol = mt*8 + lc*2;
                if (pcol < 30) {
                    f32x4 A0 = acc[mt*2+0], A1 = acc[mt*2+1];
                    float p0 = fmaxf(fmaxf(A0[0], A0[1]), fmaxf(A1[0], A1[1]));
                    float p1 = fmaxf(fmaxf(A0[2], A0[3]), fmaxf(A1[2], A1[3]));
                    float m0 = gelu_f(p0 + bias);
                    float m1 = gelu_f(p1 + bias);
                    int u0 = (rbase + pcol)*8     + (xr ^ (pcol & 7));
                    int u1 = (rbase + pcol + 1)*8 + (xr ^ ((pcol+1) & 7));
                    *(unsigned short*)(smem + OFF_P1 + u0*16 + (ch&7)*2) = f2bf(m0);
                    *(unsigned short*)(smem + OFF_P1 + u1*16 + (ch&7)*2) = f2bf(m1);
                }
            }
        } else if (i1 >= 4 && (i1 & 1) == 0) {
            // ---------- conv2 row i2: waves 4-7, nt=w-4, 2 mtiles ----------
            const int i2 = (i1 - 4) >> 1;
            f32x4 acc[4];   // [mt][row]
            #pragma unroll
            for (int i = 0; i < 4; ++i) acc[i] = (f32x4){0.f,0.f,0.f,0.f};
            #pragma unroll
            for (int pr = 0; pr < 4; ++pr) {
                int rb = ((2*i2 + pr) % 6) * 30;
                #pragma unroll
                for (int v = 0; v < 3; ++v) {
                    #pragma unroll
                    for (int mt = 0; mt < 2; ++mt) {
                        int col = mt*16 + l15 + v;
                        #pragma unroll
                        for (int kh = 0; kh < 2; ++kh) {
                            int unit = (rb + col)*8 + ((kh*4 + lc) ^ (col & 7));
                            short8 a = *(const short8*)(smem + OFF_P1 + unit*16);
                            if (pr <= 2)
                                acc[mt*2+0] = __builtin_amdgcn_mfma_f32_16x16x32_bf16(
                                    a, wf[kh*9 + pr*3+v], acc[mt*2+0], 0, 0, 0);
                            if (pr >= 1)
                                acc[mt*2+1] = __builtin_amdgcn_mfma_f32_16x16x32_bf16(
                                    a, wf[kh*9 + (pr-1)*3+v], acc[mt*2+1], 0, 0, 0);
                        }
                    }
                }
            }
            // epilogue: exact GELU x8 then max -> out
            #pragma unroll
            for (int mt = 0; mt < 2; ++mt) {
                int pcol = mt*8 + lc*2;
                if (pcol < 14) {
                    f32x4 A0 = acc[mt*2+0], A1 = acc[mt*2+1];
                    float g00 = gelu_f(A0[0] + bias), g01 = gelu_f(A0[1] + bias);
                    float g02 = gelu_f(A0[2] + bias), g03 = gelu_f(A0[3] + bias);
                    float g10 = gelu_f(A1[0] + bias), g11 = gelu_f(A1[1] + bias);
                    float g12 = gelu_f(A1[2] + bias), g13 = gelu_f(A1[3] + bias);
                    float m0 = fmaxf(fmaxf(g00, g01), fmaxf(g10, g11));
                    float m1 = fmaxf(fmaxf(g02, g03), fmaxf(g12, g13));
                    float2 st; st.x = m0; st.y = m1;
                    *(float2*)(out + obase + ch*196 + i2*14 + pcol) = st;
                }
            }
        }

        __syncthreads();   // conv1 reads of P0 done; P1 row i1 done
        if (i1 < 29) produce(smem, tys, b0r, c0w, tid, 2*i1 + 4);
    }

    __syncthreads();
    // tail: conv2 row 13 (P1 rows 26..29)
    if (w >= 4) {
        const int i2 = 13;
        f32x4 acc[4];
        #pragma unroll
        for (int i = 0; i < 4; ++i) acc[i] = (f32x4){0.f,0.f,0.f,0.f};
        #pragma unroll
        for (int pr = 0; pr < 4; ++pr) {
            int rb = ((2*i2 + pr) % 6) * 30;
            #pragma unroll
            for (int v = 0; v < 3; ++v) {
                #pragma unroll
                for (int mt = 0; mt < 2; ++mt) {
                    int col = mt*16 + l15 + v;
                    #pragma unroll
                    for (int kh = 0; kh < 2; ++kh) {
                        int unit = (rb + col)*8 + ((kh*4 + lc) ^ (col & 7));
                        short8 a = *(const short8*)(smem + OFF_P1 + unit*16);
                        if (pr <= 2)
                            acc[mt*2+0] = __builtin_amdgcn_mfma_f32_16x16x32_bf16(
                                a, wf[kh*9 + pr*3+v], acc[mt*2+0], 0, 0, 0);
                        if (pr >= 1)
                            acc[mt*2+1] = __builtin_amdgcn_mfma_f32_16x16x32_bf16(
                                a, wf[kh*9 + (pr-1)*3+v], acc[mt*2+1], 0, 0, 0);
                    }
                }
            }
        }
        #pragma unroll
        for (int mt = 0; mt < 2; ++mt) {
            int pcol = mt*8 + lc*2;
            if (pcol < 14) {
                f32x4 A0 = acc[mt*2+0], A1 = acc[mt*2+1];
                float g00 = gelu_f(A0[0] + bias), g01 = gelu_f(A0[1] + bias);
                float g02 = gelu_f(A0[2] + bias), g03 = gelu_f(A0[3] + bias);
                float g10 = gelu_f(A1[0] + bias), g11 = gelu_f(A1[1] + bias);
                float g12 = gelu_f(A1[2] + bias), g13 = gelu_f(A1[3] + bias);
                float m0 = fmaxf(fmaxf(g00, g01), fmaxf(g10, g11));
                float m1 = fmaxf(fmaxf(g02, g03), fmaxf(g12, g13));
                float2 st; st.x = m0; st.y = m1;
                *(float2*)(out + obase + ch*196 + i2*14 + pcol) = st;
            }
        }
    }
}

extern "C" void kernel_launch(void* const* d_in, const int* in_sizes, int n_in,
                              void* d_out, int out_size, void* d_ws, size_t ws_size,
                              hipStream_t stream) {
    const float* token = (const float*)d_in[0];
    const float* type_ = (const float*)d_in[1];
    const float* w0 = (const float*)d_in[2];
    const float* b0 = (const float*)d_in[3];
    const float* w1 = (const float*)d_in[4];
    const float* b1 = (const float*)d_in[5];
    const float* w2 = (const float*)d_in[6];
    const float* b2 = (const float*)d_in[7];
    float* out = (float*)d_out;

    hipLaunchKernelGGL(conv_pipeline, dim3(512), dim3(512), LDS_TOTAL, stream,
                       token, type_, w0, b0, w1, b1, w2, b2, out);
}

// Round 5
// 253.234 us; speedup vs baseline: 9.4271x; 1.0031x over previous
//
#include <hip/hip_runtime.h>

// Conv2dFusion v3: wave-specialized fused pipeline, 2 blocks/CU.
// Per image: 128x128 rank-1 map -> conv0(1->32)+GELU+pool (VALU, H-table, GELU-after-max)
//   -> conv1(32->64)+GELU+pool (MFMA, waves 0-3) -> P1 6-row LDS ring
//   -> conv2(64->64)+GELU+pool (MFMA, waves 4-7, interleaved) -> out.
// LDS 65.7KB -> 2 blocks/CU; shared wf[18] frag array keeps VGPR <= 128.

typedef short short8 __attribute__((ext_vector_type(8)));
typedef float f32x4 __attribute__((ext_vector_type(4)));

#define OFF_TY   0                    // f32[128]
#define OFF_TK   512                  // f32[128]
#define OFF_HLO  1024                 // u32[32*126]
#define OFF_HHI  (1024 + 16128)       // u16[32*126]
#define OFF_P0   (17152 + 8064)       // 25216: 4 slots * 264 units * 16B
#define OFF_P1   (25216 + 16896)      // 42112: ring 6 rows*240 units + 32 pad = 1472 units
#define LDS_TOTAL (42112 + 1472*16)   // 65,664 B

__device__ __forceinline__ unsigned short f2bf(float f) {
    unsigned int u = __float_as_uint(f);
    u += 0x7fffu + ((u >> 16) & 1u);   // RNE
    return (unsigned short)(u >> 16);
}

// erf-GELU via A&S 7.1.25 (|err| <= 2.5e-5), branch-free.
__device__ __forceinline__ float gelu_f(float x) {
    float ax = __builtin_fabsf(x);
    float E  = __builtin_amdgcn_exp2f(x * x * -0.72134752f);
    float k  = __builtin_amdgcn_rcpf(__builtin_fmaf(0.33267686f, ax, 1.0f));
    float s  = __builtin_fmaf(0.7478556f, k, -0.0958798f);
    s = __builtin_fmaf(s, k, 0.3480242f);
    s = s * k;
    float erfabs = __builtin_fmaf(-s, E, 1.0f);
    return __builtin_fmaf(0.5f * ax, erfabs, 0.5f * x);
}

// pool0 producer: pooled rows R0, R0+1 into P0 ring (GELU applied after max).
__device__ __forceinline__ void produce(char* smem, const float* tys,
                                        float b0r, int c, int tid, int R0) {
    float t0 = tys[2*R0+0], t1 = tys[2*R0+1], t2 = tys[2*R0+2],
          t3 = tys[2*R0+3], t4 = tys[2*R0+4], t5 = tys[2*R0+5];
    int rest = tid >> 5;
    #pragma unroll
    for (int k = 0; k < 8; ++k, rest += 16) {
        if (rest < 126) {
            int roff = (rest >= 63) ? 1 : 0;
            int q = rest - (roff ? 63 : 0);
            float s0 = roff ? t2 : t0;
            float s1 = roff ? t3 : t1;
            float s2 = roff ? t4 : t2;
            float s3 = roff ? t5 : t3;
            uint2 lo = *(const uint2*)(smem + OFF_HLO + (c*126 + 2*q)*4);
            unsigned int hi = *(const unsigned int*)(smem + OFF_HHI + (c*126 + 2*q)*2);
            float h00 = __uint_as_float(lo.x << 16);
            float h10 = __uint_as_float(lo.x & 0xffff0000u);
            float h01 = __uint_as_float(lo.y << 16);
            float h11 = __uint_as_float(lo.y & 0xffff0000u);
            float h20 = __uint_as_float(hi << 16);
            float h21 = __uint_as_float(hi & 0xffff0000u);
            float e00 = __builtin_fmaf(s0,h00, __builtin_fmaf(s1,h10, __builtin_fmaf(s2,h20, b0r)));
            float e10 = __builtin_fmaf(s1,h00, __builtin_fmaf(s2,h10, __builtin_fmaf(s3,h20, b0r)));
            float e01 = __builtin_fmaf(s0,h01, __builtin_fmaf(s1,h11, __builtin_fmaf(s2,h21, b0r)));
            float e11 = __builtin_fmaf(s1,h01, __builtin_fmaf(s2,h11, __builtin_fmaf(s3,h21, b0r)));
            // GELU after max (monotone for x>-0.75; bias bounded & smoothed downstream)
            float m = gelu_f(fmaxf(fmaxf(e00, e01), fmaxf(e10, e11)));
            int slot = (R0 + roff) & 3;
            int unit = slot*264 + (q>>1)*8 + ((4*(q&1) + (c>>3)) ^ ((q>>1)&7));
            *(unsigned short*)(smem + OFF_P0 + unit*16 + (c&7)*2) = f2bf(m);
        }
    }
}

__launch_bounds__(512, 4)
__global__ void conv_pipeline(const float* __restrict__ token,
                              const float* __restrict__ type_,
                              const float* __restrict__ w0, const float* __restrict__ b0,
                              const float* __restrict__ w1, const float* __restrict__ b1,
                              const float* __restrict__ w2, const float* __restrict__ b2,
                              float* __restrict__ out) {
    extern __shared__ char smem[];
    float* tys = (float*)(smem + OFF_TY);
    float* tks = (float*)(smem + OFF_TK);

    const int tid = threadIdx.x;
    const int img = blockIdx.x;
    const int w   = tid >> 6;
    const int l   = tid & 63;
    const int l15 = l & 15;
    const int lc  = l >> 4;
    const int c0w = tid & 31;

    for (int i = tid; i < 128; i += 512) {
        tys[i] = type_[img*128 + i];
        tks[i] = token[img*128 + i];
    }

    float w0r[9];
    #pragma unroll
    for (int i = 0; i < 9; ++i) w0r[i] = w0[c0w*9 + i];
    const float b0r = b0[c0w];

    // Shared fragment storage: waves 0-3 use wf[0..8] (conv1, nt=w),
    // waves 4-7 use wf[0..17] (conv2, nt=w-4, kh*9+uv).
    short8 wf[18];
    float bias;
    const int ch = ((w & 3) * 16) + l15;       // c1 (waves<4) or c2 (waves>=4)
    if (w < 4) {
        bias = b1[ch];
        #pragma unroll
        for (int uv = 0; uv < 9; ++uv) {
            short8 f;
            #pragma unroll
            for (int j = 0; j < 8; ++j)
                f[j] = (short)f2bf(w1[(ch*32 + 8*lc + j)*9 + uv]);
            wf[uv] = f;
        }
    } else {
        bias = b2[ch];
        #pragma unroll
        for (int kh = 0; kh < 2; ++kh)
            #pragma unroll
            for (int uv = 0; uv < 9; ++uv) {
                short8 f;
                #pragma unroll
                for (int j = 0; j < 8; ++j)
                    f[j] = (short)f2bf(w2[(ch*64 + kh*32 + 8*lc + j)*9 + uv]);
                wf[kh*9 + uv] = f;
            }
    }

    __syncthreads();   // ty/tk visible

    // H[c][x][u] = sum_v w0[c,u,v]*tk[x+v]
    {
        int x = tid >> 5;
        #pragma unroll
        for (int k = 0; k < 8; ++k, x += 16) {
            if (x < 126) {
                float t0 = tks[x], t1 = tks[x+1], t2 = tks[x+2];
                float h0 = __builtin_fmaf(w0r[0],t0, __builtin_fmaf(w0r[1],t1, w0r[2]*t2));
                float h1 = __builtin_fmaf(w0r[3],t0, __builtin_fmaf(w0r[4],t1, w0r[5]*t2));
                float h2 = __builtin_fmaf(w0r[6],t0, __builtin_fmaf(w0r[7],t1, w0r[8]*t2));
                unsigned int lov = (unsigned int)f2bf(h0) | ((unsigned int)f2bf(h1) << 16);
                *(unsigned int*)(smem + OFF_HLO + (c0w*126 + x)*4) = lov;
                *(unsigned short*)(smem + OFF_HHI + (c0w*126 + x)*2) = f2bf(h2);
            }
        }
    }
    __syncthreads();   // H visible

    produce(smem, tys, b0r, c0w, tid, 0);
    produce(smem, tys, b0r, c0w, tid, 2);

    const size_t obase = (size_t)img * 12544;

    for (int i1 = 0; i1 < 30; ++i1) {
        __syncthreads();   // P0 strip + P1[i1-1] visible

        if (w < 4) {
            // ---------- conv1 row i1: waves 0-3, nt=w, all 4 mtiles ----------
            f32x4 acc[8];   // [mt][row]
            #pragma unroll
            for (int i = 0; i < 8; ++i) acc[i] = (f32x4){0.f,0.f,0.f,0.f};
            #pragma unroll
            for (int pr = 0; pr < 4; ++pr) {
                int sbase = ((2*i1 + pr) & 3) * 264;
                #pragma unroll
                for (int v = 0; v < 3; ++v) {
                    #pragma unroll
                    for (int mt = 0; mt < 4; ++mt) {
                        int col = mt*16 + l15 + v;
                        int unit = sbase + (col>>1)*8 + ((4*(col&1) + lc) ^ ((col>>1)&7));
                        short8 a = *(const short8*)(smem + OFF_P0 + unit*16);
                        if (pr <= 2)
                            acc[mt*2+0] = __builtin_amdgcn_mfma_f32_16x16x32_bf16(
                                a, wf[pr*3+v], acc[mt*2+0], 0, 0, 0);
                        if (pr >= 1)
                            acc[mt*2+1] = __builtin_amdgcn_mfma_f32_16x16x32_bf16(
                                a, wf[(pr-1)*3+v], acc[mt*2+1], 0, 0, 0);
                    }
                }
            }
            // epilogue: premax -> +bias -> GELU -> P1 ring row i1%6
            int rbase = (i1 % 6) * 30;
            int xr = ch >> 3;
            #pragma unroll
            for (int mt = 0; mt < 4; ++mt) {
                int pcol = mt*8 + lc*2;
                if (pcol < 30) {
                    f32x4 A0 = acc[mt*2+0], A1 = acc[mt*2+1];
                    float p0 = fmaxf(fmaxf(A0[0], A0[1]), fmaxf(A1[0], A1[1]));
                    float p1 = fmaxf(fmaxf(A0[2], A0[3]), fmaxf(A1[2], A1[3]));
                    float m0 = gelu_f(p0 + bias);
                    float m1 = gelu_f(p1 + bias);
                    int u0 = (rbase + pcol)*8     + (xr ^ (pcol & 7));
                    int u1 = (rbase + pcol + 1)*8 + (xr ^ ((pcol+1) & 7));
                    *(unsigned short*)(smem + OFF_P1 + u0*16 + (ch&7)*2) = f2bf(m0);
                    *(unsigned short*)(smem + OFF_P1 + u1*16 + (ch&7)*2) = f2bf(m1);
                }
            }
        } else if (i1 >= 4 && (i1 & 1) == 0) {
            // ---------- conv2 row i2: waves 4-7, nt=w-4, 2 mtiles ----------
            const int i2 = (i1 - 4) >> 1;
            f32x4 acc[4];   // [mt][row]
            #pragma unroll
            for (int i = 0; i < 4; ++i) acc[i] = (f32x4){0.f,0.f,0.f,0.f};
            #pragma unroll
            for (int pr = 0; pr < 4; ++pr) {
                int rb = ((2*i2 + pr) % 6) * 30;
                #pragma unroll
                for (int v = 0; v < 3; ++v) {
                    #pragma unroll
                    for (int mt = 0; mt < 2; ++mt) {
                        int col = mt*16 + l15 + v;
                        #pragma unroll
                        for (int kh = 0; kh < 2; ++kh) {
                            int unit = (rb + col)*8 + ((kh*4 + lc) ^ (col & 7));
                            short8 a = *(const short8*)(smem + OFF_P1 + unit*16);
                            if (pr <= 2)
                                acc[mt*2+0] = __builtin_amdgcn_mfma_f32_16x16x32_bf16(
                                    a, wf[kh*9 + pr*3+v], acc[mt*2+0], 0, 0, 0);
                            if (pr >= 1)
                                acc[mt*2+1] = __builtin_amdgcn_mfma_f32_16x16x32_bf16(
                                    a, wf[kh*9 + (pr-1)*3+v], acc[mt*2+1], 0, 0, 0);
                        }
                    }
                }
            }
            // epilogue: exact GELU x8 then max -> out
            #pragma unroll
            for (int mt = 0; mt < 2; ++mt) {
                int pcol = mt*8 + lc*2;
                if (pcol < 14) {
                    f32x4 A0 = acc[mt*2+0], A1 = acc[mt*2+1];
                    float g00 = gelu_f(A0[0] + bias), g01 = gelu_f(A0[1] + bias);
                    float g02 = gelu_f(A0[2] + bias), g03 = gelu_f(A0[3] + bias);
                    float g10 = gelu_f(A1[0] + bias), g11 = gelu_f(A1[1] + bias);
                    float g12 = gelu_f(A1[2] + bias), g13 = gelu_f(A1[3] + bias);
                    float m0 = fmaxf(fmaxf(g00, g01), fmaxf(g10, g11));
                    float m1 = fmaxf(fmaxf(g02, g03), fmaxf(g12, g13));
                    float2 st; st.x = m0; st.y = m1;
                    *(float2*)(out + obase + ch*196 + i2*14 + pcol) = st;
                }
            }
        }

        __syncthreads();   // conv1 reads of P0 done; P1 row i1 done
        if (i1 < 29) produce(smem, tys, b0r, c0w, tid, 2*i1 + 4);
    }

    __syncthreads();
    // tail: conv2 row 13 (P1 rows 26..29)
    if (w >= 4) {
        const int i2 = 13;
        f32x4 acc[4];
        #pragma unroll
        for (int i = 0; i < 4; ++i) acc[i] = (f32x4){0.f,0.f,0.f,0.f};
        #pragma unroll
        for (int pr = 0; pr < 4; ++pr) {
            int rb = ((2*i2 + pr) % 6) * 30;
            #pragma unroll
            for (int v = 0; v < 3; ++v) {
                #pragma unroll
                for (int mt = 0; mt < 2; ++mt) {
                    int col = mt*16 + l15 + v;
                    #pragma unroll
                    for (int kh = 0; kh < 2; ++kh) {
                        int unit = (rb + col)*8 + ((kh*4 + lc) ^ (col & 7));
                        short8 a = *(const short8*)(smem + OFF_P1 + unit*16);
                        if (pr <= 2)
                            acc[mt*2+0] = __builtin_amdgcn_mfma_f32_16x16x32_bf16(
                                a, wf[kh*9 + pr*3+v], acc[mt*2+0], 0, 0, 0);
                        if (pr >= 1)
                            acc[mt*2+1] = __builtin_amdgcn_mfma_f32_16x16x32_bf16(
                                a, wf[kh*9 + (pr-1)*3+v], acc[mt*2+1], 0, 0, 0);
                    }
                }
            }
        }
        #pragma unroll
        for (int mt = 0; mt < 2; ++mt) {
            int pcol = mt*8 + lc*2;
            if (pcol < 14) {
                f32x4 A0 = acc[mt*2+0], A1 = acc[mt*2+1];
                float g00 = gelu_f(A0[0] + bias), g01 = gelu_f(A0[1] + bias);
                float g02 = gelu_f(A0[2] + bias), g03 = gelu_f(A0[3] + bias);
                float g10 = gelu_f(A1[0] + bias), g11 = gelu_f(A1[1] + bias);
                float g12 = gelu_f(A1[2] + bias), g13 = gelu_f(A1[3] + bias);
                float m0 = fmaxf(fmaxf(g00, g01), fmaxf(g10, g11));
                float m1 = fmaxf(fmaxf(g02, g03), fmaxf(g12, g13));
                float2 st; st.x = m0; st.y = m1;
                *(float2*)(out + obase + ch*196 + i2*14 + pcol) = st;
            }
        }
    }
}

extern "C" void kernel_launch(void* const* d_in, const int* in_sizes, int n_in,
                              void* d_out, int out_size, void* d_ws, size_t ws_size,
                              hipStream_t stream) {
    const float* token = (const float*)d_in[0];
    const float* type_ = (const float*)d_in[1];
    const float* w0 = (const float*)d_in[2];
    const float* b0 = (const float*)d_in[3];
    const float* w1 = (const float*)d_in[4];
    const float* b1 = (const float*)d_in[5];
    const float* w2 = (const float*)d_in[6];
    const float* b2 = (const float*)d_in[7];
    float* out = (float*)d_out;

    hipLaunchKernelGGL(conv_pipeline, dim3(512), dim3(512), LDS_TOTAL, stream,
                       token, type_, w0, b0, w1, b1, w2, b2, out);
}